// Round 9
// baseline (20.869 us; speedup 1.0000x reference)
//
#include <hip/hip_runtime.h>

#define VOCAB 1024
#define ARCS  16
#define CHAIN 3
#define START_STATE 0
#define WAVE 64
#define WAVES_PER_BLOCK 4
#define BLOCK (WAVE * WAVES_PER_BLOCK)
#define QUART (VOCAB / WAVES_PER_BLOCK)   // 256 labels per wave

typedef float f32x4 __attribute__((ext_vector_type(4)));
typedef int   i32x4 __attribute__((ext_vector_type(4)));

// ONE HYPOTHESIS PER BLOCK, 4 waves each owning a 256-label quarter.
// Grid = B blocks = 32 blocks/CU = 4 pipelined generations, so later blocks'
// dependent-load preambles hide under earlier blocks' store drain.
// Each wave independently (no barriers): chain walk (scalar, redundant),
// 48-arc fetch (redundant, L1-amortized within the CU), commits in-range
// labels to a wave-private 256B who-table (u8 owner lane, 0xFF = none),
// merges via ds_bpermute from its own lanes' registers, stores 2KB.
__global__ __launch_bounds__(BLOCK, 8) void ngram_advance_kernel(
    const float* __restrict__ arcs_weights,
    const float* __restrict__ backoff_weights,
    const int*   __restrict__ ilabels,
    const int*   __restrict__ to_states,
    const int*   __restrict__ backoff_to,
    const int*   __restrict__ state_start,
    const int*   __restrict__ state_end,
    const int*   __restrict__ states,
    float*       __restrict__ out_scores,   // [B, V]
    float*       __restrict__ out_next)     // [B, V] state ids as f32
{
    __shared__ unsigned char s_who[WAVES_PER_BLOCK][QUART];  // 1 KB total

    const int lane = threadIdx.x & (WAVE - 1);
    const int wid  = __builtin_amdgcn_readfirstlane(threadIdx.x >> 6);
    const int b    = blockIdx.x;
    const int base = wid * QUART;                 // this wave's label range

    unsigned char* __restrict__ who = s_who[wid];

    // ---- 1. Kick off the dependent chain immediately (uniform -> s_load).
    int cur = states[b];

    // ---- 2. Sentinel-init own 256B who-table (one ds_write_b32 per lane).
    *(unsigned*)&who[lane * 4] = 0xFFFFFFFFu;
    __builtin_amdgcn_sched_barrier(0);

    // ---- 3. Chain walk, branchless (backoff_weights[0]==0, backoff_to[0]==0:
    // START self-loops at zero cost). Wave-uniform -> scalarized.
    float acc = 0.0f;
    const int   cs0 = cur;  const float ca0 = acc;
    acc += backoff_weights[cur];  cur = backoff_to[cur];
    const int   cs1 = cur;  const float ca1 = acc;
    acc += backoff_weights[cur];  cur = backoff_to[cur];
    const int   cs2 = cur;  const float ca2 = acc;
    acc += backoff_weights[cur];
    const float accf = acc;

    // ---- 4. Arc fetch: lanes 0..47, level = lane>>4, arc = lane&15. ----
    const int level = lane >> 4;
    const int arc   = lane & (ARCS - 1);
    int   lab = -1;
    float sc  = 0.0f, fns = 0.0f;
    bool  ok  = false;
    if (lane < CHAIN * ARCS) {
        const int   s    = (level == 0) ? cs0 : (level == 1) ? cs1 : cs2;
        const float cacc = (level == 0) ? ca0 : (level == 1) ? ca1 : ca2;
        if (s != START_STATE) {
            const int idx = state_start[s] + arc;
            if (idx < state_end[s]) {
                lab = ilabels[idx];
                sc  = cacc + arcs_weights[idx];
                fns = (float)to_states[idx];
                ok  = true;
            }
        }
    }
    const unsigned lv = (unsigned)(lab - base);   // local label, <256 if ours

    // ---- 5. Ordered who-commits (level 2 -> 1 -> 0), masked to this wave's
    // label range. Same-wave LDS ops are program-ordered; level 0 (highest
    // n-gram order) commits last and wins = reference first-write-wins.
    // Within a level labels are unique (builder sorts unique per state).
    if (ok && level == 2 && lv < QUART) who[lv] = (unsigned char)lane;
    __builtin_amdgcn_sched_barrier(0);
    if (ok && level == 1 && lv < QUART) who[lv] = (unsigned char)lane;
    __builtin_amdgcn_sched_barrier(0);
    if (ok && level == 0 && lv < QUART) who[lv] = (unsigned char)lane;
    __builtin_amdgcn_sched_barrier(0);

    // ---- 6. Merge + store this wave's 256-label slice (1 f32x4 per array).
    const int gv = base + lane * 4;               // global label of elem 0
    const unsigned w4 = *(const unsigned*)&who[lane * 4];
    const f32x4 dwv = *(const f32x4*)&arcs_weights[gv];  // L1-hot dense table
    const i32x4 dnv = *(const i32x4*)&to_states[gv];     // L1-hot dense table
    const int sci = __float_as_int(sc);
    const int nsi = __float_as_int(fns);
    f32x4 rs, rx;
    #pragma unroll
    for (int j = 0; j < 4; ++j) {
        const unsigned wb = (w4 >> (8 * j)) & 0xFFu;
        const float scv = __int_as_float(
            __builtin_amdgcn_ds_bpermute((int)(wb << 2), sci));
        const float nsv = __int_as_float(
            __builtin_amdgcn_ds_bpermute((int)(wb << 2), nsi));
        const bool hit = (wb != 0xFFu);
        rs[j] = hit ? scv : accf + dwv[j];
        rx[j] = hit ? nsv : (float)dnv[j];
    }
    *(f32x4*)&out_scores[(size_t)b * VOCAB + gv] = rs;
    *(f32x4*)&out_next  [(size_t)b * VOCAB + gv] = rx;
}

extern "C" void kernel_launch(void* const* d_in, const int* in_sizes, int n_in,
                              void* d_out, int out_size, void* d_ws, size_t ws_size,
                              hipStream_t stream) {
    const float* arcs_weights    = (const float*)d_in[0];
    const float* backoff_weights = (const float*)d_in[1];
    const int*   ilabels         = (const int*)d_in[2];
    const int*   to_states       = (const int*)d_in[3];
    const int*   backoff_to      = (const int*)d_in[4];
    const int*   state_start     = (const int*)d_in[5];
    const int*   state_end       = (const int*)d_in[6];
    const int*   states          = (const int*)d_in[7];

    const int B = in_sizes[7];                           // 8192 hypotheses
    float* out_scores = (float*)d_out;                   // first B*V floats
    float* out_next   = out_scores + (size_t)B * VOCAB;  // second B*V

    ngram_advance_kernel<<<B, BLOCK, 0, stream>>>(
        arcs_weights, backoff_weights, ilabels, to_states, backoff_to,
        state_start, state_end, states, out_scores, out_next);
}